// Round 4
// baseline (3924.829 us; speedup 1.0000x reference)
//
#include <hip/hip_runtime.h>
#include <hip/hip_fp16.h>

#define TT   2048
#define BB   64
#define II   16
#define HH   8
#define HIDN 64
#define GG   256   // 4*HIDN
#define T4   (TT / 4)

typedef _Float16 h2 __attribute__((ext_vector_type(2)));
typedef _Float16 h4 __attribute__((ext_vector_type(4)));
typedef _Float16 h8 __attribute__((ext_vector_type(8)));

__device__ __forceinline__ float fdot2(h2 a, h2 b, float c) {
    return __builtin_amdgcn_fdot2(a, b, c, false);
}
__device__ __forceinline__ float fast_sigmoid(float z) {
    return __builtin_amdgcn_rcpf(1.0f + __expf(-z));
}
__device__ __forceinline__ float fast_tanh(float z) {
    return fmaf(2.0f, __builtin_amdgcn_rcpf(1.0f + __expf(-2.0f * z)), -1.0f);
}

// ---------------- x -> f16 conversion (one-time, trivial) ----------------
__global__ void cvt_x_kernel(const float* __restrict__ x, _Float16* __restrict__ xh, int n4) {
    int i = blockIdx.x * blockDim.x + threadIdx.x;
    if (i < n4) {
        float4 v = ((const float4*)x)[i];
        ((h2*)xh)[2 * i]     = h2{ (_Float16)v.x, (_Float16)v.y };
        ((h2*)xh)[2 * i + 1] = h2{ (_Float16)v.z, (_Float16)v.w };
    }
}

// ---------------- main recurrent kernel: 4 chains per wave ----------------
// R2/R3 post-mortem: ANY cross-wave h-exchange (ds_write+drain+barrier+
// ds_read) costs ~1000 cyc/step regardless of wave count; the barrier-free
// fdot2 design costs ~420 issue + ~740 IDLE stall cyc/step. So: keep the
// barrier-free wave-local structure and fill the idle cycles with 3 more
// independent chains. Chains share the head's weights (~160 VGPR); each has
// private hbuf/cst/x-prefetch. All LDS is wave-local (in-order pipe, no
// barriers); the 4 chains' reads/dots/gates interleave so each chain's
// latency hides under the others' issue. Expected: issue-bound at ~440-650
// cyc/step amortized vs 1160 today.
__global__ __launch_bounds__(64, 1)
void lstm_wave4(const _Float16* __restrict__ xh,
                const float* __restrict__ Wih,
                const float* __restrict__ Whh,
                const float* __restrict__ bih,
                const float* __restrict__ bhh,
                _Float16* __restrict__ stage_f16)   // [t4][chain][unit][4] h4
{
    const int lane = threadIdx.x;                   // hidden unit index
    const int hd   = blockIdx.x >> 4;               // head
    const int b0   = (blockIdx.x & 15) << 2;        // first of 4 batches

    // ---- shared per-lane weights: the 4 gate rows of this unit, f16 ----
    h2 whh[4][HIDN / 2];
    h2 wih[4][II / 2];
    float bias[4];
#pragma unroll
    for (int g = 0; g < 4; ++g) {
        const int r = hd * GG + g * HIDN + lane;    // PyTorch gate-major row
        const float4* p = (const float4*)(Whh + (size_t)r * HIDN);
#pragma unroll
        for (int q = 0; q < HIDN / 4; ++q) {
            float4 v = p[q];
            whh[g][2 * q]     = h2{ (_Float16)v.x, (_Float16)v.y };
            whh[g][2 * q + 1] = h2{ (_Float16)v.z, (_Float16)v.w };
        }
        const float4* pi = (const float4*)(Wih + (size_t)r * II);
#pragma unroll
        for (int q = 0; q < II / 4; ++q) {
            float4 v = pi[q];
            wih[g][2 * q]     = h2{ (_Float16)v.x, (_Float16)v.y };
            wih[g][2 * q + 1] = h2{ (_Float16)v.z, (_Float16)v.w };
        }
        bias[g] = bih[r] + bhh[r];
    }

    // ---- 4 private h buffers (wave-synchronous, in-order LDS pipe) ----
    __shared__ __align__(16) _Float16 hb[4][HIDN];
#pragma unroll
    for (int c = 0; c < 4; ++c) hb[c][lane] = (_Float16)0.0f;

    float cst[4] = {0.f, 0.f, 0.f, 0.f};

    const _Float16* xb0 = xh + (size_t)(b0 + 0) * II;
    const _Float16* xb1 = xh + (size_t)(b0 + 1) * II;
    const _Float16* xb2 = xh + (size_t)(b0 + 2) * II;
    const _Float16* xb3 = xh + (size_t)(b0 + 3) * II;

    h2 xv[4][II / 2], xn[4][II / 2];
    auto ldx = [&](const _Float16* base, int t, h2* dst) {
        // broadcast 32B load; t may over-read by 1 step into workspace slack
        const h8* p = (const h8*)(base + (size_t)t * (BB * II));
        union { h8 v; h2 p2[4]; } u0, u1;
        u0.v = p[0];
        u1.v = p[1];
#pragma unroll
        for (int i = 0; i < 4; ++i) { dst[i] = u0.p2[i]; dst[4 + i] = u1.p2[i]; }
    };
    ldx(xb0, 0, xv[0]); ldx(xb1, 0, xv[1]); ldx(xb2, 0, xv[2]); ldx(xb3, 0, xv[3]);

    // slab: h4 index = chain_id*64 + lane; chain c at +c*64
    h4* sp = (h4*)stage_f16 + (size_t)(hd * 64 + b0) * 64 + lane;

    for (int t4 = 0; t4 < T4; ++t4) {
        const int t0 = 4 * t4;
        union { h4 v4; _Float16 e[4]; } hpk[4];
#pragma unroll
        for (int j = 0; j < 4; ++j) {
            const int t = t0 + j;

            // prefetch x(t+1) for all chains (consumed next step)
            ldx(xb0, t + 1, xn[0]); ldx(xb1, t + 1, xn[1]);
            ldx(xb2, t + 1, xn[2]); ldx(xb3, t + 1, xn[3]);

            // all 4 chains' h broadcast-reads issued up front (latency
            // amortized across the 32 reads; conflict-free broadcast)
            union { h8 v[8]; h2 p[32]; } hr[4];
#pragma unroll
            for (int c = 0; c < 4; ++c)
#pragma unroll
                for (int q = 0; q < 8; ++q) hr[c].v[q] = ((const h8*)hb[c])[q];

            float z[4][4];
#pragma unroll
            for (int c = 0; c < 4; ++c)
#pragma unroll
                for (int g = 0; g < 4; ++g) z[c][g] = bias[g];

            // q-major / chain-minor: 16 independent accumulator chains
#pragma unroll
            for (int q = 0; q < HIDN / 2; ++q)
#pragma unroll
                for (int c = 0; c < 4; ++c) {
                    z[c][0] = fdot2(whh[0][q], hr[c].p[q], z[c][0]);
                    z[c][1] = fdot2(whh[1][q], hr[c].p[q], z[c][1]);
                    z[c][2] = fdot2(whh[2][q], hr[c].p[q], z[c][2]);
                    z[c][3] = fdot2(whh[3][q], hr[c].p[q], z[c][3]);
                }
#pragma unroll
            for (int q = 0; q < II / 2; ++q)
#pragma unroll
                for (int c = 0; c < 4; ++c) {
                    z[c][0] = fdot2(wih[0][q], xv[c][q], z[c][0]);
                    z[c][1] = fdot2(wih[1][q], xv[c][q], z[c][1]);
                    z[c][2] = fdot2(wih[2][q], xv[c][q], z[c][2]);
                    z[c][3] = fdot2(wih[3][q], xv[c][q], z[c][3]);
                }

#pragma unroll
            for (int c = 0; c < 4; ++c) {
                float gi = fast_sigmoid(z[c][0]);
                float gf = fast_sigmoid(z[c][1]);
                float gg = fast_tanh(z[c][2]);
                float go = fast_sigmoid(z[c][3]);
                cst[c] = fmaf(gf, cst[c], gi * gg);
                float hv = go * fast_tanh(cst[c]);
                _Float16 h16 = (_Float16)hv;
                hb[c][lane] = h16;          // in-order after this step's reads
                hpk[c].e[j] = h16;
            }
#pragma unroll
            for (int c = 0; c < 4; ++c)
#pragma unroll
                for (int q = 0; q < II / 2; ++q) xv[c][q] = xn[c][q];
        }
#pragma unroll
        for (int c = 0; c < 4; ++c)
            sp[c * 64] = hpk[c].v4;         // 8B fire-and-forget
        sp += 512 * 64;
    }
}

// ---------------- legacy one-wave-per-chain kernel (workspace fallback) ----------------
template <int STAGE, bool XF16>
__global__ __launch_bounds__(64, 1)
void lstm_wave(const float* __restrict__ x,
               const _Float16* __restrict__ xh,
               const float* __restrict__ Wih,
               const float* __restrict__ Whh,
               const float* __restrict__ bih,
               const float* __restrict__ bhh,
               const float* __restrict__ Wlin,
               const float* __restrict__ blin,
               float* __restrict__ out,
               float* __restrict__ lstm_out,
               _Float16* __restrict__ stage_f16)
{
    const int lane = threadIdx.x;
    const int c    = blockIdx.x;
    const int b    = c & (BB - 1);
    const int hd   = c >> 6;

    h2 whh[4][HIDN / 2];
    h2 wih[4][II / 2];
    float bias[4];
#pragma unroll
    for (int g = 0; g < 4; ++g) {
        const int r = hd * GG + g * HIDN + lane;
        const float4* p = (const float4*)(Whh + (size_t)r * HIDN);
#pragma unroll
        for (int q = 0; q < HIDN / 4; ++q) {
            float4 v = p[q];
            whh[g][2 * q]     = h2{ (_Float16)v.x, (_Float16)v.y };
            whh[g][2 * q + 1] = h2{ (_Float16)v.z, (_Float16)v.w };
        }
        const float4* pi = (const float4*)(Wih + (size_t)r * II);
#pragma unroll
        for (int q = 0; q < II / 4; ++q) {
            float4 v = pi[q];
            wih[g][2 * q]     = h2{ (_Float16)v.x, (_Float16)v.y };
            wih[g][2 * q + 1] = h2{ (_Float16)v.z, (_Float16)v.w };
        }
        bias[g] = bih[r] + bhh[r];
    }
    float wl = 0.0f, blv = 0.0f;
    if (STAGE == 2) { wl = Wlin[hd * HIDN + lane]; blv = blin[hd]; }

    __shared__ __align__(16) _Float16 hbuf[HIDN];
    hbuf[lane] = (_Float16)0.0f;

    float cst = 0.0f;

    const _Float16* xhp = xh + b * II;
    const float*    xfp = x + b * II;
    h2 xv[II / 2];
    auto load_x = [&](int t, h2* dst) {
        int tc = t < TT ? t : TT - 1;
        if (XF16) {
            const h8* p = (const h8*)(xhp + (size_t)tc * BB * II);
            union { h8 v; h2 p2[4]; } u0, u1;
            u0.v = p[0];
            u1.v = p[1];
#pragma unroll
            for (int i = 0; i < 4; ++i) { dst[i] = u0.p2[i]; dst[4 + i] = u1.p2[i]; }
        } else {
            const float4* p = (const float4*)(xfp + (size_t)tc * BB * II);
#pragma unroll
            for (int q = 0; q < 4; ++q) {
                float4 v = p[q];
                dst[2 * q]     = h2{ (_Float16)v.x, (_Float16)v.y };
                dst[2 * q + 1] = h2{ (_Float16)v.z, (_Float16)v.w };
            }
        }
    };
    load_x(0, xv);

    h4* sptr = (h4*)(stage_f16 + (size_t)c * 256 + lane * 4);

    for (int t4 = 0; t4 < T4; ++t4) {
        union { h4 v4; h2 p2[2]; } hp;
#pragma unroll
        for (int j = 0; j < 4; ++j) {
            const int t = t4 * 4 + j;
            h2 xn[II / 2];
            load_x(t + 1, xn);

            union { h8 v[8]; h2 p[32]; } hr;
#pragma unroll
            for (int q = 0; q < 8; ++q) hr.v[q] = ((const h8*)hbuf)[q];

            float z0 = bias[0], z1 = bias[1], z2 = bias[2], z3 = bias[3];
#pragma unroll
            for (int q = 0; q < HIDN / 2; ++q) {
                z0 = fdot2(whh[0][q], hr.p[q], z0);
                z1 = fdot2(whh[1][q], hr.p[q], z1);
                z2 = fdot2(whh[2][q], hr.p[q], z2);
                z3 = fdot2(whh[3][q], hr.p[q], z3);
            }
#pragma unroll
            for (int q = 0; q < II / 2; ++q) {
                z0 = fdot2(wih[0][q], xv[q], z0);
                z1 = fdot2(wih[1][q], xv[q], z1);
                z2 = fdot2(wih[2][q], xv[q], z2);
                z3 = fdot2(wih[3][q], xv[q], z3);
            }

            float gi = fast_sigmoid(z0);
            float gf = fast_sigmoid(z1);
            float gg = fast_tanh(z2);
            float go = fast_sigmoid(z3);

            cst = fmaf(gf, cst, gi * gg);
            float h = go * fast_tanh(cst);
            _Float16 h16 = (_Float16)h;

            hbuf[lane] = h16;
            hp.p2[j >> 1][j & 1] = h16;

            if (STAGE == 2) {
                atomicAdd(&lstm_out[((size_t)t * BB + b) * HIDN + lane], h);
                float p = h * wl;
                p += __shfl_down(p, 32, 64);
                p += __shfl_down(p, 16, 64);
                p += __shfl_down(p, 8, 64);
                p += __shfl_down(p, 4, 64);
                p += __shfl_down(p, 2, 64);
                p += __shfl_down(p, 1, 64);
                if (lane == 0) out[((size_t)t * BB + b) * HH + hd] = p + blv;
            }

#pragma unroll
            for (int q = 0; q < II / 2; ++q) xv[q] = xn[q];
        }
        if (STAGE == 1) {
            *sptr = hp.v4;
            sptr += 512 * 64;
        }
    }
}

// ---------------- pass 2a: lstm_out[t,b,k] = sum_hd h ----------------
__global__ __launch_bounds__(256)
void pass_lstm(const _Float16* __restrict__ stage, float* __restrict__ lstm_out)
{
    const int tid  = threadIdx.x;
    const int k    = tid & (HIDN - 1);
    const int q    = tid >> 6;
    const int b    = blockIdx.x & (BB - 1);
    const int tile = blockIdx.x >> 6;
    const h4* sp = (const h4*)stage;

#pragma unroll
    for (int g = 0; g < 4; ++g) {
        const int t4 = tile * 16 + q + 4 * g;
        float acc0 = 0.f, acc1 = 0.f, acc2 = 0.f, acc3 = 0.f;
#pragma unroll
        for (int hd = 0; hd < HH; ++hd) {
            h4 v = sp[((size_t)t4 * 512 + hd * 64 + b) * 64 + k];
            acc0 += (float)v.x; acc1 += (float)v.y;
            acc2 += (float)v.z; acc3 += (float)v.w;
        }
        const size_t t = (size_t)t4 * 4;
        lstm_out[((t + 0) * BB + b) * HIDN + k] = acc0;
        lstm_out[((t + 1) * BB + b) * HIDN + k] = acc1;
        lstm_out[((t + 2) * BB + b) * HIDN + k] = acc2;
        lstm_out[((t + 3) * BB + b) * HIDN + k] = acc3;
    }
}

// ---------------- pass 2b: out[t,b,hd] = dot(h, W_lin)+b_lin ----------------
__global__ __launch_bounds__(512)
void pass_out(const _Float16* __restrict__ stage,
              const float* __restrict__ Wlin,
              const float* __restrict__ blin,
              float* __restrict__ out)
{
    __shared__ float wls[GG * 2];
    const int tid = threadIdx.x;
    wls[tid] = Wlin[tid];
    __syncthreads();

    const int b  = tid >> 3;
    const int hd = tid & 7;
    const int c  = hd * 64 + b;
    const int t4 = blockIdx.x;
    const float bl = blin[hd];

    const h4* sp = (const h4*)stage + ((size_t)t4 * 512 + c) * 64;
    float a0 = 0.f, a1 = 0.f, a2 = 0.f, a3 = 0.f;
#pragma unroll 8
    for (int k = 0; k < HIDN; ++k) {
        h4 v = sp[k];
        float w = wls[hd * HIDN + k];
        a0 = fmaf((float)v.x, w, a0);
        a1 = fmaf((float)v.y, w, a1);
        a2 = fmaf((float)v.z, w, a2);
        a3 = fmaf((float)v.w, w, a3);
    }
    const size_t t = (size_t)t4 * 4;
    out[(t + 0) * 512 + tid] = a0 + bl;
    out[(t + 1) * 512 + tid] = a1 + bl;
    out[(t + 2) * 512 + tid] = a2 + bl;
    out[(t + 3) * 512 + tid] = a3 + bl;
}

extern "C" void kernel_launch(void* const* d_in, const int* in_sizes, int n_in,
                              void* d_out, int out_size, void* d_ws, size_t ws_size,
                              hipStream_t stream)
{
    const float* x    = (const float*)d_in[0];
    const float* Wih  = (const float*)d_in[1];
    const float* Whh  = (const float*)d_in[2];
    const float* bih  = (const float*)d_in[3];
    const float* bhh  = (const float*)d_in[4];
    const float* Wlin = (const float*)d_in[5];
    const float* blin = (const float*)d_in[6];

    float* out  = (float*)d_out;
    float* lstm = out + (size_t)TT * BB * HH;

    const size_t xbytes = (size_t)TT * BB * II * 2 + 4096;   // 4 MB + prefetch slack
    const size_t slab16 = (size_t)TT * BB * HH * HIDN * 2;   // 134 MB

    const bool xf16 = ws_size >= xbytes;
    _Float16* xh = (_Float16*)d_ws;
    char* slabp  = (char*)d_ws + (xf16 ? xbytes : 0);
    size_t avail = ws_size - (xf16 ? xbytes : 0);
    const int mode = (avail >= slab16) ? 1 : 2;

    if (xf16) {
        int n4 = TT * BB * II / 4;
        cvt_x_kernel<<<(n4 + 255) / 256, 256, 0, stream>>>(x, xh, n4);
    }

    _Float16* sh = (_Float16*)slabp;

    if (mode == 1 && xf16) {
        // 4-chain-per-wave barrier-free path: 128 blocks x 64 threads
        lstm_wave4<<<dim3(HH * 16), dim3(64), 0, stream>>>(xh, Wih, Whh, bih, bhh, sh);
        pass_lstm<<<dim3(BB * 32), dim3(256), 0, stream>>>(sh, lstm);
        pass_out <<<dim3(T4), dim3(512), 0, stream>>>(sh, Wlin, blin, out);
    } else if (mode == 1) {
        dim3 grid(BB * HH), block(64);
        lstm_wave<1, false><<<grid, block, 0, stream>>>(x, xh, Wih, Whh, bih, bhh,
                                                        Wlin, blin, out, lstm, sh);
        pass_lstm<<<dim3(BB * 32), dim3(256), 0, stream>>>(sh, lstm);
        pass_out <<<dim3(T4), dim3(512), 0, stream>>>(sh, Wlin, blin, out);
    } else {
        hipMemsetAsync(lstm, 0, (size_t)TT * BB * HIDN * 4, stream);
        dim3 grid(BB * HH), block(64);
        if (xf16)
            lstm_wave<2, true><<<grid, block, 0, stream>>>(x, xh, Wih, Whh, bih, bhh,
                                                           Wlin, blin, out, lstm, sh);
        else
            lstm_wave<2, false><<<grid, block, 0, stream>>>(x, xh, Wih, Whh, bih, bhh,
                                                            Wlin, blin, out, lstm, sh);
    }
}

// Round 5
// 1169.200 us; speedup vs baseline: 3.3569x; 3.3569x over previous
//
#include <hip/hip_runtime.h>
#include <hip/hip_fp16.h>

#define TT   2048
#define BB   64
#define II   16
#define HH   8
#define HIDN 64
#define GG   256   // 4*HIDN
#define T4   (TT / 4)

typedef _Float16 h2 __attribute__((ext_vector_type(2)));
typedef _Float16 h4 __attribute__((ext_vector_type(4)));
typedef _Float16 h8 __attribute__((ext_vector_type(8)));

__device__ __forceinline__ float fdot2(h2 a, h2 b, float c) {
    return __builtin_amdgcn_fdot2(a, b, c, false);
}
__device__ __forceinline__ float fast_sigmoid(float z) {
    return __builtin_amdgcn_rcpf(1.0f + __expf(-z));
}
__device__ __forceinline__ float fast_tanh(float z) {
    return fmaf(2.0f, __builtin_amdgcn_rcpf(1.0f + __expf(-2.0f * z)), -1.0f);
}

// ---------------- x -> f16 conversion (one-time, trivial) ----------------
__global__ void cvt_x_kernel(const float* __restrict__ x, _Float16* __restrict__ xh, int n4) {
    int i = blockIdx.x * blockDim.x + threadIdx.x;
    if (i < n4) {
        float4 v = ((const float4*)x)[i];
        ((h2*)xh)[2 * i]     = h2{ (_Float16)v.x, (_Float16)v.y };
        ((h2*)xh)[2 * i + 1] = h2{ (_Float16)v.z, (_Float16)v.w };
    }
}

// ------------- main recurrent kernel: SGPR-broadcast h, zero LDS -----------
// One wave per chain (512 blocks x 64 threads), as in the 991us baseline.
// R0 stall decomposition: 1160 cyc/step = ~420 issue + ~740 stall, dominated
// by the LDS h round-trip (ds_write -> in-order pipe -> 8x ds_read_b128 ->
// lgkmcnt) with nothing co-resident to hide it (1 wave/SIMD). The h operand
// of every dot is WAVE-UNIFORM, so broadcast it through SGPRs instead:
//   h16 (per lane) --v_mov_dpp(quad_perm swap)--> partner h16
//   pack pair {h[2*floor(L/2)], h[2*floor(L/2)+1]} per lane (RNE, numerics
//   identical to the LDS version)
//   32x v_readlane(packed, 2q) -> SGPRs; fdot2 uses the SGPR as its one
//   allowed scalar operand.
// No ds ops, no lgkmcnt in the loop; h(t)->z(t+1) path is ~25 cyc of VALU.
// R4 lesson (VGPR=216 + scratch spill at 4 chains/wave): stay at 1 chain,
// ~180 VGPRs, no spill.
__global__ __launch_bounds__(64, 1)
void lstm_rl(const _Float16* __restrict__ xh,
             const float* __restrict__ Wih,
             const float* __restrict__ Whh,
             const float* __restrict__ bih,
             const float* __restrict__ bhh,
             _Float16* __restrict__ stage_f16)   // [t4][chain][unit][4] h4
{
    const int lane = threadIdx.x;          // hidden unit index
    const int c    = blockIdx.x;           // chain id
    const int b    = c & (BB - 1);
    const int hd   = c >> 6;
    const bool odd = lane & 1;

    // ---- per-lane weights: the 4 gate rows of this unit, f16 in VGPRs ----
    h2 whh[4][HIDN / 2];
    h2 wih[4][II / 2];
    float bias[4];
#pragma unroll
    for (int g = 0; g < 4; ++g) {
        const int r = hd * GG + g * HIDN + lane;  // PyTorch gate-major row
        const float4* p = (const float4*)(Whh + (size_t)r * HIDN);
#pragma unroll
        for (int q = 0; q < HIDN / 4; ++q) {
            float4 v = p[q];
            whh[g][2 * q]     = h2{ (_Float16)v.x, (_Float16)v.y };
            whh[g][2 * q + 1] = h2{ (_Float16)v.z, (_Float16)v.w };
        }
        const float4* pi = (const float4*)(Wih + (size_t)r * II);
#pragma unroll
        for (int q = 0; q < II / 4; ++q) {
            float4 v = pi[q];
            wih[g][2 * q]     = h2{ (_Float16)v.x, (_Float16)v.y };
            wih[g][2 * q + 1] = h2{ (_Float16)v.z, (_Float16)v.w };
        }
        bias[g] = bih[r] + bhh[r];
    }

    float cst   = 0.0f;
    int  packed = 0;                      // h(-1) pair = {0,0}

    const _Float16* xhp = xh + b * II;
    h2 xv[II / 2], xn[II / 2];
    auto ldx = [&](int t, h2* dst) {
        // 32B broadcast load; t==TT over-reads into workspace slack (safe)
        const h8* p = (const h8*)(xhp + (size_t)t * BB * II);
        union { h8 v; h2 p2[4]; } u0, u1;
        u0.v = p[0];
        u1.v = p[1];
#pragma unroll
        for (int i = 0; i < 4; ++i) { dst[i] = u0.p2[i]; dst[4 + i] = u1.p2[i]; }
    };
    ldx(0, xv);

    h4* sptr = (h4*)(stage_f16 + (size_t)c * 256 + lane * 4);

    for (int t4 = 0; t4 < T4; ++t4) {
        union { h4 v4; _Float16 e[4]; } hpk;
#pragma unroll
        for (int j = 0; j < 4; ++j) {
            const int t = t4 * 4 + j;
            ldx(t + 1, xn);               // consumed next step (vmcnt-covered)

            float z0 = bias[0], z1 = bias[1], z2 = bias[2], z3 = bias[3];
            // x-projection first (independent of h broadcast)
#pragma unroll
            for (int q = 0; q < II / 2; ++q) {
                z0 = fdot2(wih[0][q], xv[q], z0);
                z1 = fdot2(wih[1][q], xv[q], z1);
                z2 = fdot2(wih[2][q], xv[q], z2);
                z3 = fdot2(wih[3][q], xv[q], z3);
            }
            // h-projection: wave-uniform h2 pairs via readlane -> SGPR
#pragma unroll
            for (int q = 0; q < HIDN / 2; ++q) {
                h2 hq = __builtin_bit_cast(h2,
                            __builtin_amdgcn_readlane(packed, 2 * q));
                z0 = fdot2(whh[0][q], hq, z0);
                z1 = fdot2(whh[1][q], hq, z1);
                z2 = fdot2(whh[2][q], hq, z2);
                z3 = fdot2(whh[3][q], hq, z3);
            }

            float gi = fast_sigmoid(z0);
            float gf = fast_sigmoid(z1);
            float gg = fast_tanh(z2);
            float go = fast_sigmoid(z3);

            cst = fmaf(gf, cst, gi * gg);
            float hv = go * fast_tanh(cst);
            _Float16 h16 = (_Float16)hv;   // RNE, same numerics as LDS version
            hpk.e[j] = h16;

            // pack {h[2*floor(L/2)], h[2*floor(L/2)+1]} for next step
            int h32 = (int)__builtin_bit_cast(unsigned short, h16);
            int hsw = __builtin_amdgcn_mov_dpp(h32, 0xB1, 0xF, 0xF, true); // lane^1
            int lo  = odd ? hsw : h32;
            int hi  = odd ? h32 : hsw;
            packed  = lo | (hi << 16);

#pragma unroll
            for (int q = 0; q < II / 2; ++q) xv[q] = xn[q];
        }
        *sptr = hpk.v4;                   // 8B fire-and-forget, acks amortized x4
        sptr += 512 * 64;
    }
}

// ---------------- legacy one-wave-per-chain kernel (fallback modes) ----------------
template <int STAGE, bool XF16>
__global__ __launch_bounds__(64, 1)
void lstm_wave(const float* __restrict__ x,
               const _Float16* __restrict__ xh,
               const float* __restrict__ Wih,
               const float* __restrict__ Whh,
               const float* __restrict__ bih,
               const float* __restrict__ bhh,
               const float* __restrict__ Wlin,
               const float* __restrict__ blin,
               float* __restrict__ out,
               float* __restrict__ lstm_out,
               _Float16* __restrict__ stage_f16)
{
    const int lane = threadIdx.x;
    const int c    = blockIdx.x;
    const int b    = c & (BB - 1);
    const int hd   = c >> 6;

    h2 whh[4][HIDN / 2];
    h2 wih[4][II / 2];
    float bias[4];
#pragma unroll
    for (int g = 0; g < 4; ++g) {
        const int r = hd * GG + g * HIDN + lane;
        const float4* p = (const float4*)(Whh + (size_t)r * HIDN);
#pragma unroll
        for (int q = 0; q < HIDN / 4; ++q) {
            float4 v = p[q];
            whh[g][2 * q]     = h2{ (_Float16)v.x, (_Float16)v.y };
            whh[g][2 * q + 1] = h2{ (_Float16)v.z, (_Float16)v.w };
        }
        const float4* pi = (const float4*)(Wih + (size_t)r * II);
#pragma unroll
        for (int q = 0; q < II / 4; ++q) {
            float4 v = pi[q];
            wih[g][2 * q]     = h2{ (_Float16)v.x, (_Float16)v.y };
            wih[g][2 * q + 1] = h2{ (_Float16)v.z, (_Float16)v.w };
        }
        bias[g] = bih[r] + bhh[r];
    }
    float wl = 0.0f, blv = 0.0f;
    if (STAGE == 2) { wl = Wlin[hd * HIDN + lane]; blv = blin[hd]; }

    __shared__ __align__(16) _Float16 hbuf[HIDN];
    hbuf[lane] = (_Float16)0.0f;

    float cst = 0.0f;

    const _Float16* xhp = xh + b * II;
    const float*    xfp = x + b * II;
    h2 xv[II / 2];
    auto load_x = [&](int t, h2* dst) {
        int tc = t < TT ? t : TT - 1;
        if (XF16) {
            const h8* p = (const h8*)(xhp + (size_t)tc * BB * II);
            union { h8 v; h2 p2[4]; } u0, u1;
            u0.v = p[0];
            u1.v = p[1];
#pragma unroll
            for (int i = 0; i < 4; ++i) { dst[i] = u0.p2[i]; dst[4 + i] = u1.p2[i]; }
        } else {
            const float4* p = (const float4*)(xfp + (size_t)tc * BB * II);
#pragma unroll
            for (int q = 0; q < 4; ++q) {
                float4 v = p[q];
                dst[2 * q]     = h2{ (_Float16)v.x, (_Float16)v.y };
                dst[2 * q + 1] = h2{ (_Float16)v.z, (_Float16)v.w };
            }
        }
    };
    load_x(0, xv);

    h4* sptr = (h4*)(stage_f16 + (size_t)c * 256 + lane * 4);

    for (int t4 = 0; t4 < T4; ++t4) {
        union { h4 v4; h2 p2[2]; } hp;
#pragma unroll
        for (int j = 0; j < 4; ++j) {
            const int t = t4 * 4 + j;
            h2 xn[II / 2];
            load_x(t + 1, xn);

            union { h8 v[8]; h2 p[32]; } hr;
#pragma unroll
            for (int q = 0; q < 8; ++q) hr.v[q] = ((const h8*)hbuf)[q];

            float z0 = bias[0], z1 = bias[1], z2 = bias[2], z3 = bias[3];
#pragma unroll
            for (int q = 0; q < HIDN / 2; ++q) {
                z0 = fdot2(whh[0][q], hr.p[q], z0);
                z1 = fdot2(whh[1][q], hr.p[q], z1);
                z2 = fdot2(whh[2][q], hr.p[q], z2);
                z3 = fdot2(whh[3][q], hr.p[q], z3);
            }
#pragma unroll
            for (int q = 0; q < II / 2; ++q) {
                z0 = fdot2(wih[0][q], xv[q], z0);
                z1 = fdot2(wih[1][q], xv[q], z1);
                z2 = fdot2(wih[2][q], xv[q], z2);
                z3 = fdot2(wih[3][q], xv[q], z3);
            }

            float gi = fast_sigmoid(z0);
            float gf = fast_sigmoid(z1);
            float gg = fast_tanh(z2);
            float go = fast_sigmoid(z3);

            cst = fmaf(gf, cst, gi * gg);
            float h = go * fast_tanh(cst);
            _Float16 h16 = (_Float16)h;

            hbuf[lane] = h16;
            hp.p2[j >> 1][j & 1] = h16;

            if (STAGE == 2) {
                atomicAdd(&lstm_out[((size_t)t * BB + b) * HIDN + lane], h);
                float p = h * wl;
                p += __shfl_down(p, 32, 64);
                p += __shfl_down(p, 16, 64);
                p += __shfl_down(p, 8, 64);
                p += __shfl_down(p, 4, 64);
                p += __shfl_down(p, 2, 64);
                p += __shfl_down(p, 1, 64);
                if (lane == 0) out[((size_t)t * BB + b) * HH + hd] = p + blv;
            }

#pragma unroll
            for (int q = 0; q < II / 2; ++q) xv[q] = xn[q];
        }
        if (STAGE == 1) {
            *sptr = hp.v4;
            sptr += 512 * 64;
        }
    }
}

// ---------------- pass 2a: lstm_out[t,b,k] = sum_hd h ----------------
__global__ __launch_bounds__(256)
void pass_lstm(const _Float16* __restrict__ stage, float* __restrict__ lstm_out)
{
    const int tid  = threadIdx.x;
    const int k    = tid & (HIDN - 1);
    const int q    = tid >> 6;
    const int b    = blockIdx.x & (BB - 1);
    const int tile = blockIdx.x >> 6;
    const h4* sp = (const h4*)stage;

#pragma unroll
    for (int g = 0; g < 4; ++g) {
        const int t4 = tile * 16 + q + 4 * g;
        float acc0 = 0.f, acc1 = 0.f, acc2 = 0.f, acc3 = 0.f;
#pragma unroll
        for (int hd = 0; hd < HH; ++hd) {
            h4 v = sp[((size_t)t4 * 512 + hd * 64 + b) * 64 + k];
            acc0 += (float)v.x; acc1 += (float)v.y;
            acc2 += (float)v.z; acc3 += (float)v.w;
        }
        const size_t t = (size_t)t4 * 4;
        lstm_out[((t + 0) * BB + b) * HIDN + k] = acc0;
        lstm_out[((t + 1) * BB + b) * HIDN + k] = acc1;
        lstm_out[((t + 2) * BB + b) * HIDN + k] = acc2;
        lstm_out[((t + 3) * BB + b) * HIDN + k] = acc3;
    }
}

// ---------------- pass 2b: out[t,b,hd] = dot(h, W_lin)+b_lin ----------------
__global__ __launch_bounds__(512)
void pass_out(const _Float16* __restrict__ stage,
              const float* __restrict__ Wlin,
              const float* __restrict__ blin,
              float* __restrict__ out)
{
    __shared__ float wls[GG * 2];
    const int tid = threadIdx.x;
    wls[tid] = Wlin[tid];
    __syncthreads();

    const int b  = tid >> 3;
    const int hd = tid & 7;
    const int c  = hd * 64 + b;
    const int t4 = blockIdx.x;
    const float bl = blin[hd];

    const h4* sp = (const h4*)stage + ((size_t)t4 * 512 + c) * 64;
    float a0 = 0.f, a1 = 0.f, a2 = 0.f, a3 = 0.f;
#pragma unroll 8
    for (int k = 0; k < HIDN; ++k) {
        h4 v = sp[k];
        float w = wls[hd * HIDN + k];
        a0 = fmaf((float)v.x, w, a0);
        a1 = fmaf((float)v.y, w, a1);
        a2 = fmaf((float)v.z, w, a2);
        a3 = fmaf((float)v.w, w, a3);
    }
    const size_t t = (size_t)t4 * 4;
    out[(t + 0) * 512 + tid] = a0 + bl;
    out[(t + 1) * 512 + tid] = a1 + bl;
    out[(t + 2) * 512 + tid] = a2 + bl;
    out[(t + 3) * 512 + tid] = a3 + bl;
}

extern "C" void kernel_launch(void* const* d_in, const int* in_sizes, int n_in,
                              void* d_out, int out_size, void* d_ws, size_t ws_size,
                              hipStream_t stream)
{
    const float* x    = (const float*)d_in[0];
    const float* Wih  = (const float*)d_in[1];
    const float* Whh  = (const float*)d_in[2];
    const float* bih  = (const float*)d_in[3];
    const float* bhh  = (const float*)d_in[4];
    const float* Wlin = (const float*)d_in[5];
    const float* blin = (const float*)d_in[6];

    float* out  = (float*)d_out;
    float* lstm = out + (size_t)TT * BB * HH;

    const size_t xbytes = (size_t)TT * BB * II * 2 + 4096;   // 4 MB + prefetch slack
    const size_t slab16 = (size_t)TT * BB * HH * HIDN * 2;   // 134 MB

    const bool xf16 = ws_size >= xbytes;
    _Float16* xh = (_Float16*)d_ws;
    char* slabp  = (char*)d_ws + (xf16 ? xbytes : 0);
    size_t avail = ws_size - (xf16 ? xbytes : 0);
    const int mode = (avail >= slab16) ? 1 : 2;

    if (xf16) {
        int n4 = TT * BB * II / 4;
        cvt_x_kernel<<<(n4 + 255) / 256, 256, 0, stream>>>(x, xh, n4);
    }

    _Float16* sh = (_Float16*)slabp;

    if (mode == 1 && xf16) {
        // SGPR-broadcast recurrent kernel: 512 blocks x 64 threads, zero LDS
        lstm_rl<<<dim3(BB * HH), dim3(64), 0, stream>>>(xh, Wih, Whh, bih, bhh, sh);
        pass_lstm<<<dim3(BB * 32), dim3(256), 0, stream>>>(sh, lstm);
        pass_out <<<dim3(T4), dim3(512), 0, stream>>>(sh, Wlin, blin, out);
    } else if (mode == 1) {
        dim3 grid(BB * HH), block(64);
        lstm_wave<1, false><<<grid, block, 0, stream>>>(x, xh, Wih, Whh, bih, bhh,
                                                        Wlin, blin, out, lstm, sh);
        pass_lstm<<<dim3(BB * 32), dim3(256), 0, stream>>>(sh, lstm);
        pass_out <<<dim3(T4), dim3(512), 0, stream>>>(sh, Wlin, blin, out);
    } else {
        hipMemsetAsync(lstm, 0, (size_t)TT * BB * HIDN * 4, stream);
        dim3 grid(BB * HH), block(64);
        if (xf16)
            lstm_wave<2, true><<<grid, block, 0, stream>>>(x, xh, Wih, Whh, bih, bhh,
                                                           Wlin, blin, out, lstm, sh);
        else
            lstm_wave<2, false><<<grid, block, 0, stream>>>(x, xh, Wih, Whh, bih, bhh,
                                                            Wlin, blin, out, lstm, sh);
    }
}